// Round 4
// baseline (739.311 us; speedup 1.0000x reference)
//
#include <hip/hip_runtime.h>
#include <hip/hip_bf16.h>
#include <cstdint>
#include <cstddef>

#define N_NODES 100000
#define N_EDGES 1600000
#define F_IN 512
#define H1F 64
#define H2F 32
#define NCF 16

// ---------------------------------------------------------------------------
// Degree histogram over dst (real edges only; self-loop added as +1 later)
// ---------------------------------------------------------------------------
__global__ __launch_bounds__(256) void hist_kernel(const int* __restrict__ dst,
                                                   int* __restrict__ cnt) {
    int e = blockIdx.x * 256 + threadIdx.x;
    if (e < N_EDGES) atomicAdd(&cnt[dst[e]], 1);
}

// ---------------------------------------------------------------------------
// Two-level exclusive scan of cnt[N] -> row_ptr[N+1]; chunk = 512
// ---------------------------------------------------------------------------
__global__ __launch_bounds__(512) void scanA_kernel(const int* __restrict__ cnt,
                                                    int* __restrict__ bsums) {
    __shared__ int sh[8];
    int i = blockIdx.x * 512 + threadIdx.x;
    int v = (i < N_NODES) ? cnt[i] : 0;
    #pragma unroll
    for (int o = 32; o > 0; o >>= 1) v += __shfl_down(v, o);
    if ((threadIdx.x & 63) == 0) sh[threadIdx.x >> 6] = v;
    __syncthreads();
    if (threadIdx.x == 0) {
        int t = 0;
        #pragma unroll
        for (int w = 0; w < 8; ++w) t += sh[w];
        bsums[blockIdx.x] = t;
    }
}

__global__ __launch_bounds__(256) void scanB_kernel(int* __restrict__ bsums, int n) {
    __shared__ int s[256];
    int t = threadIdx.x;
    int v = (t < n) ? bsums[t] : 0;
    s[t] = v;
    __syncthreads();
    for (int o = 1; o < 256; o <<= 1) {
        int a = (t >= o) ? s[t - o] : 0;
        __syncthreads();
        s[t] += a;
        __syncthreads();
    }
    if (t < n) bsums[t] = s[t] - v;   // exclusive
}

__global__ __launch_bounds__(512) void scanC_kernel(const int* __restrict__ cnt,
                                                    const int* __restrict__ bsums,
                                                    int* __restrict__ row_ptr,
                                                    int* __restrict__ cursor) {
    __shared__ int s[512];
    int t = threadIdx.x;
    int i = blockIdx.x * 512 + t;
    int v = (i < N_NODES) ? cnt[i] : 0;
    s[t] = v;
    __syncthreads();
    for (int o = 1; o < 512; o <<= 1) {
        int a = (t >= o) ? s[t - o] : 0;
        __syncthreads();
        s[t] += a;
        __syncthreads();
    }
    if (i < N_NODES) {
        int ex = s[t] - v + bsums[blockIdx.x];
        row_ptr[i] = ex;
        cursor[i]  = ex;
    }
    if (i == N_NODES - 1) row_ptr[N_NODES] = s[t] + bsums[blockIdx.x];
}

// ---------------------------------------------------------------------------
// dinv[i] = rsqrt(cnt[i] + 1)   (self-loop => degree >= 1, no zero case)
// ---------------------------------------------------------------------------
__global__ __launch_bounds__(256) void dinv_kernel(const int* __restrict__ cnt,
                                                   float* __restrict__ dinv) {
    int i = blockIdx.x * 256 + threadIdx.x;
    if (i < N_NODES) dinv[i] = rsqrtf((float)(cnt[i] + 1));
}

// ---------------------------------------------------------------------------
// CSR scatter: col[row_ptr[dst] + k] = src
// ---------------------------------------------------------------------------
__global__ __launch_bounds__(256) void scatter_kernel(const int* __restrict__ src,
                                                      const int* __restrict__ dst,
                                                      int* __restrict__ cursor,
                                                      int* __restrict__ col) {
    int e = blockIdx.x * 256 + threadIdx.x;
    if (e < N_EDGES) {
        int d = dst[e];
        int pos = atomicAdd(&cursor[d], 1);
        col[pos] = src[e];
    }
}

// ---------------------------------------------------------------------------
// GEMM1: out[r][c] = dinv[r] * sum_k x[r][k] * W[k][c]     (M=100000,K=512,N=64)
// BM=128, BN=64, BK=32, 256 threads, 8x4 acc per thread
// ---------------------------------------------------------------------------
__global__ __launch_bounds__(256) void gemm1_kernel(const float* __restrict__ x,
                                                    const float* __restrict__ W,
                                                    const float* __restrict__ dinv,
                                                    float* __restrict__ out) {
    __shared__ float xs[32][132];   // [BK][BM+4], row stride 528B (16B aligned)
    __shared__ float ws[32][68];    // [BK][BN+4], row stride 272B (16B aligned)
    int tid = threadIdx.x;
    int brow = blockIdx.x * 128;
    int tr = tid >> 4;   // 0..15 -> 8 rows each
    int tc = tid & 15;   // 0..15 -> 4 cols each
    float acc[8][4] = {};

    for (int kb = 0; kb < F_IN; kb += 32) {
        // x tile: 128 rows x 32 k, transposed into xs[k][r]
        #pragma unroll
        for (int i = 0; i < 4; ++i) {
            int f = tid + i * 256;      // float4 index 0..1023
            int r = f >> 3;             // 0..127
            int k4 = f & 7;             // 0..7
            int gr = brow + r;
            float4 v = make_float4(0.f, 0.f, 0.f, 0.f);
            if (gr < N_NODES)
                v = *reinterpret_cast<const float4*>(&x[(size_t)gr * F_IN + kb + k4 * 4]);
            xs[k4 * 4 + 0][r] = v.x;
            xs[k4 * 4 + 1][r] = v.y;
            xs[k4 * 4 + 2][r] = v.z;
            xs[k4 * 4 + 3][r] = v.w;
        }
        // W tile: 32 k x 64 c
        #pragma unroll
        for (int i = 0; i < 2; ++i) {
            int f = tid + i * 256;      // float4 index 0..511
            int k = f >> 4;             // 0..31
            int c4 = f & 15;            // 0..15
            float4 v = *reinterpret_cast<const float4*>(&W[(size_t)(kb + k) * H1F + c4 * 4]);
            *reinterpret_cast<float4*>(&ws[k][c4 * 4]) = v;
        }
        __syncthreads();
        #pragma unroll
        for (int k = 0; k < 32; ++k) {
            float xv[8], wv[4];
            #pragma unroll
            for (int j = 0; j < 8; ++j) xv[j] = xs[k][tr * 8 + j];
            #pragma unroll
            for (int j = 0; j < 4; ++j) wv[j] = ws[k][tc * 4 + j];
            #pragma unroll
            for (int a = 0; a < 8; ++a)
                #pragma unroll
                for (int b = 0; b < 4; ++b) acc[a][b] += xv[a] * wv[b];
        }
        __syncthreads();
    }

    #pragma unroll
    for (int a = 0; a < 8; ++a) {
        int gr = brow + tr * 8 + a;
        if (gr < N_NODES) {
            float dv = dinv[gr];
            float4 v = make_float4(acc[a][0] * dv, acc[a][1] * dv,
                                   acc[a][2] * dv, acc[a][3] * dv);
            *reinterpret_cast<float4*>(&out[(size_t)gr * H1F + tc * 4]) = v;
        }
    }
}

// ---------------------------------------------------------------------------
// GEMM2: [N][64] @ [64][32], scaled by dinv.  8 rows/block.
// ---------------------------------------------------------------------------
__global__ __launch_bounds__(256) void gemm2_kernel(const float* __restrict__ h,
                                                    const float* __restrict__ W,
                                                    const float* __restrict__ dinv,
                                                    float* __restrict__ out) {
    __shared__ float ws[64][32];
    __shared__ float rs[8][64];
    int tid = threadIdx.x;
    int brow = blockIdx.x * 8;
    #pragma unroll
    for (int i = 0; i < 2; ++i) {
        int f = tid + i * 256;   // 0..511 float4
        reinterpret_cast<float4*>(&ws[0][0])[f] = reinterpret_cast<const float4*>(W)[f];
    }
    if (tid < 128) {
        // 8 rows x 64 = 512 floats = 128 float4, contiguous
        float4 v = reinterpret_cast<const float4*>(h)[(size_t)brow * 16 + tid];
        reinterpret_cast<float4*>(&rs[0][0])[tid] = v;
    }
    __syncthreads();
    int lr = tid >> 5;   // 0..7
    int c = tid & 31;
    float acc = 0.f;
    #pragma unroll
    for (int k = 0; k < 64; ++k) acc += rs[lr][k] * ws[k][c];
    int gr = brow + lr;
    out[(size_t)gr * H2F + c] = acc * dinv[gr];
}

// ---------------------------------------------------------------------------
// GEMM3: [N][32] @ [32][16], scaled by dinv.  16 rows/block.
// ---------------------------------------------------------------------------
__global__ __launch_bounds__(256) void gemm3_kernel(const float* __restrict__ h,
                                                    const float* __restrict__ W,
                                                    const float* __restrict__ dinv,
                                                    float* __restrict__ out) {
    __shared__ float ws[32][16];   // 512 floats
    __shared__ float rs[16][32];   // 512 floats
    int tid = threadIdx.x;
    int brow = blockIdx.x * 16;
    if (tid < 128) {
        reinterpret_cast<float4*>(&ws[0][0])[tid] = reinterpret_cast<const float4*>(W)[tid];
    } else {
        int t = tid - 128;   // 0..127 float4 of 16 rows x 32
        float4 v = reinterpret_cast<const float4*>(h)[(size_t)brow * 8 + t];
        reinterpret_cast<float4*>(&rs[0][0])[t] = v;
    }
    __syncthreads();
    int lr = tid >> 4;   // 0..15
    int c = tid & 15;
    float acc = 0.f;
    #pragma unroll
    for (int k = 0; k < 32; ++k) acc += rs[lr][k] * ws[k][c];
    int gr = brow + lr;
    out[(size_t)gr * NCF + c] = acc * dinv[gr];
}

// ---------------------------------------------------------------------------
// Aggregate: out[n][f] = act( dinv[n] * (sum_{src in CSR[n]} h[src][f] + h[n][f]) + b[f] )
// One F-lane group per node; gathers are coalesced F*4B rows.
// ---------------------------------------------------------------------------
template <int F, bool RELU, bool LSM>
__global__ __launch_bounds__(256) void aggregate_kernel(const float* __restrict__ h,
                                                        const int* __restrict__ row_ptr,
                                                        const int* __restrict__ col,
                                                        const float* __restrict__ dinv,
                                                        const float* __restrict__ bias,
                                                        float* __restrict__ out) {
    int tid = blockIdx.x * 256 + threadIdx.x;
    int n = tid / F;
    int f = tid % F;
    if (n >= N_NODES) return;
    int beg = row_ptr[n];
    int end = row_ptr[n + 1];
    float sum = h[(size_t)n * F + f];   // self-loop term (h already scaled by dinv)
    int j = beg;
    for (; j + 1 < end; j += 2) {
        int c0 = col[j];
        int c1 = col[j + 1];
        sum += h[(size_t)c0 * F + f];
        sum += h[(size_t)c1 * F + f];
    }
    if (j < end) sum += h[(size_t)col[j] * F + f];

    float val = sum * dinv[n] + bias[f];
    if (RELU) val = fmaxf(val, 0.f);
    if (LSM) {
        float m = val;
        #pragma unroll
        for (int o = 1; o < F; o <<= 1) m = fmaxf(m, __shfl_xor(m, o));
        float ex = expf(val - m);
        float s = ex;
        #pragma unroll
        for (int o = 1; o < F; o <<= 1) s += __shfl_xor(s, o);
        val = val - m - logf(s);
    }
    out[(size_t)n * F + f] = val;
}

// ---------------------------------------------------------------------------
extern "C" void kernel_launch(void* const* d_in, const int* in_sizes, int n_in,
                              void* d_out, int out_size, void* d_ws, size_t ws_size,
                              hipStream_t stream) {
    const float* x  = (const float*)d_in[0];
    const int*   ei = (const int*)d_in[1];
    const float* W1 = (const float*)d_in[2];
    const float* b1 = (const float*)d_in[3];
    const float* W2 = (const float*)d_in[4];
    const float* b2 = (const float*)d_in[5];
    const float* W3 = (const float*)d_in[6];
    const float* b3 = (const float*)d_in[7];
    float* out = (float*)d_out;

    const int* src = ei;              // edge_index[0]
    const int* dst = ei + N_EDGES;    // edge_index[1]

    char* ws = (char*)d_ws;
    size_t off = 0;
    auto alloc = [&](size_t bytes) -> void* {
        void* p = ws + off;
        off += (bytes + 255) & ~(size_t)255;
        return p;
    };
    int*   cnt     = (int*)alloc((size_t)N_NODES * 4);
    int*   row_ptr = (int*)alloc((size_t)(N_NODES + 1) * 4);
    int*   cursor  = (int*)alloc((size_t)N_NODES * 4);
    int*   bsums   = (int*)alloc(1024);
    float* dinv    = (float*)alloc((size_t)N_NODES * 4);
    int*   col     = (int*)alloc((size_t)N_EDGES * 4);
    float* bufA    = (float*)alloc((size_t)N_NODES * 64 * 4);
    float* bufB    = (float*)alloc((size_t)N_NODES * 64 * 4);

    const int nChunks = (N_NODES + 511) / 512;   // 196

    hipMemsetAsync(cnt, 0, (size_t)N_NODES * 4, stream);
    hist_kernel<<<(N_EDGES + 255) / 256, 256, 0, stream>>>(dst, cnt);
    scanA_kernel<<<nChunks, 512, 0, stream>>>(cnt, bsums);
    scanB_kernel<<<1, 256, 0, stream>>>(bsums, nChunks);
    scanC_kernel<<<nChunks, 512, 0, stream>>>(cnt, bsums, row_ptr, cursor);
    dinv_kernel<<<(N_NODES + 255) / 256, 256, 0, stream>>>(cnt, dinv);
    scatter_kernel<<<(N_EDGES + 255) / 256, 256, 0, stream>>>(src, dst, cursor, col);

    // Layer 1: x @ W1 (scaled) -> bufA ; aggregate+bias+relu -> bufB
    gemm1_kernel<<<(N_NODES + 127) / 128, 256, 0, stream>>>(x, W1, dinv, bufA);
    aggregate_kernel<64, true, false><<<(N_NODES * 64) / 256, 256, 0, stream>>>(
        bufA, row_ptr, col, dinv, b1, bufB);

    // Layer 2: bufB @ W2 (scaled) -> bufA ; aggregate+bias+relu -> bufB
    gemm2_kernel<<<N_NODES / 8, 256, 0, stream>>>(bufB, W2, dinv, bufA);
    aggregate_kernel<32, true, false><<<(N_NODES * 32) / 256, 256, 0, stream>>>(
        bufA, row_ptr, col, dinv, b2, bufB);

    // Layer 3: bufB @ W3 (scaled) -> bufA ; aggregate+bias+log_softmax -> out
    gemm3_kernel<<<N_NODES / 16, 256, 0, stream>>>(bufB, W3, dinv, bufA);
    aggregate_kernel<16, false, true><<<(N_NODES * 16) / 256, 256, 0, stream>>>(
        bufA, row_ptr, col, dinv, b3, out);
}

// Round 6
// 667.871 us; speedup vs baseline: 1.1070x; 1.1070x over previous
//
#include <hip/hip_runtime.h>
#include <hip/hip_bf16.h>
#include <cstdint>
#include <cstddef>

#define N_NODES 100000
#define N_EDGES 1600000
#define F_IN 512
#define H1F 64
#define H2F 32
#define NCF 16

typedef __attribute__((ext_vector_type(8))) short bf16x8;
typedef __attribute__((ext_vector_type(4))) float f32x4;

__device__ inline short f2bf(float f) {
    // RNE f32 -> bf16 (inputs are finite, no NaN handling needed)
    uint32_t u = __builtin_bit_cast(uint32_t, f);
    return (short)((u + 0x7FFF + ((u >> 16) & 1)) >> 16);
}

// ---------------------------------------------------------------------------
// Degree histogram over dst (real edges only; self-loop added as +1 later)
// ---------------------------------------------------------------------------
__global__ __launch_bounds__(256) void hist_kernel(const int* __restrict__ dst,
                                                   int* __restrict__ cnt) {
    int e = blockIdx.x * 256 + threadIdx.x;
    if (e < N_EDGES) atomicAdd(&cnt[dst[e]], 1);
}

// ---------------------------------------------------------------------------
// Two-level exclusive scan of cnt[N] -> row_ptr[N+1]; chunk = 512
// ---------------------------------------------------------------------------
__global__ __launch_bounds__(512) void scanA_kernel(const int* __restrict__ cnt,
                                                    int* __restrict__ bsums) {
    __shared__ int sh[8];
    int i = blockIdx.x * 512 + threadIdx.x;
    int v = (i < N_NODES) ? cnt[i] : 0;
    #pragma unroll
    for (int o = 32; o > 0; o >>= 1) v += __shfl_down(v, o);
    if ((threadIdx.x & 63) == 0) sh[threadIdx.x >> 6] = v;
    __syncthreads();
    if (threadIdx.x == 0) {
        int t = 0;
        #pragma unroll
        for (int w = 0; w < 8; ++w) t += sh[w];
        bsums[blockIdx.x] = t;
    }
}

__global__ __launch_bounds__(256) void scanB_kernel(int* __restrict__ bsums, int n) {
    __shared__ int s[256];
    int t = threadIdx.x;
    int v = (t < n) ? bsums[t] : 0;
    s[t] = v;
    __syncthreads();
    for (int o = 1; o < 256; o <<= 1) {
        int a = (t >= o) ? s[t - o] : 0;
        __syncthreads();
        s[t] += a;
        __syncthreads();
    }
    if (t < n) bsums[t] = s[t] - v;   // exclusive
}

__global__ __launch_bounds__(512) void scanC_kernel(const int* __restrict__ cnt,
                                                    const int* __restrict__ bsums,
                                                    int* __restrict__ row_ptr,
                                                    int* __restrict__ cursor) {
    __shared__ int s[512];
    int t = threadIdx.x;
    int i = blockIdx.x * 512 + t;
    int v = (i < N_NODES) ? cnt[i] : 0;
    s[t] = v;
    __syncthreads();
    for (int o = 1; o < 512; o <<= 1) {
        int a = (t >= o) ? s[t - o] : 0;
        __syncthreads();
        s[t] += a;
        __syncthreads();
    }
    if (i < N_NODES) {
        int ex = s[t] - v + bsums[blockIdx.x];
        row_ptr[i] = ex;
        cursor[i]  = ex;
    }
    if (i == N_NODES - 1) row_ptr[N_NODES] = s[t] + bsums[blockIdx.x];
}

// ---------------------------------------------------------------------------
// dinv[i] = rsqrt(cnt[i] + 1)
// ---------------------------------------------------------------------------
__global__ __launch_bounds__(256) void dinv_kernel(const int* __restrict__ cnt,
                                                   float* __restrict__ dinv) {
    int i = blockIdx.x * 256 + threadIdx.x;
    if (i < N_NODES) dinv[i] = rsqrtf((float)(cnt[i] + 1));
}

// ---------------------------------------------------------------------------
// CSR scatter: col[row_ptr[dst] + k] = src
// ---------------------------------------------------------------------------
__global__ __launch_bounds__(256) void scatter_kernel(const int* __restrict__ src,
                                                      const int* __restrict__ dst,
                                                      int* __restrict__ cursor,
                                                      int* __restrict__ col) {
    int e = blockIdx.x * 256 + threadIdx.x;
    if (e < N_EDGES) {
        int d = dst[e];
        int pos = atomicAdd(&cursor[d], 1);
        col[pos] = src[e];
    }
}

// ---------------------------------------------------------------------------
// GEMM1 (bf16 MFMA): out[r][c] = dinv[r] * sum_k x[r][k]*W[k][c]
// M=100000, K=512, N=64. BM=128, BK=32, 256 threads = 4 waves,
// wave-tile 32 rows x 64 cols, mfma_f32_16x16x32_bf16, f32 accum.
// LDS: As[2][4 kg][128 r][8] bf16 (r XOR (kg<<2) swizzle),
//      Bs[2][64 c][32 k] bf16 (byte k-chunk XOR ((c&3)<<4) swizzle,
//      2-bit key — 3-bit key would escape the 64B column and collide).
// 24 KB total.
// ---------------------------------------------------------------------------
__global__ __launch_bounds__(256) void gemm1_mfma(const float* __restrict__ x,
                                                  const float* __restrict__ W,
                                                  const float* __restrict__ dinv,
                                                  float* __restrict__ out) {
    __shared__ short As[2][4096];   // [kg]*1024 + (r ^ (kg<<2))*8 + i
    __shared__ short Bs[2][2048];   // byte: c*64 + ((kglocal*16) ^ ((c&3)<<4))
    const int tid = threadIdx.x;
    const int L = tid & 63;
    const int w = tid >> 6;          // wave 0..3
    const int brow = blockIdx.x * 128;

    f32x4 acc[2][4] = {};

    // --- staging: x-tile (k-tile kt) -> As[buf]
    auto stageA = [&](int kt, int buf) {
        #pragma unroll
        for (int h = 0; h < 2; ++h) {
            int r  = (tid >> 2) + h * 64;   // 0..127
            int kg = tid & 3;               // k-group of 8
            int gr = brow + r;
            float4 v0 = make_float4(0.f, 0.f, 0.f, 0.f);
            float4 v1 = make_float4(0.f, 0.f, 0.f, 0.f);
            if (gr < N_NODES) {
                const float* p = &x[(size_t)gr * F_IN + kt * 32 + kg * 8];
                v0 = *reinterpret_cast<const float4*>(p);
                v1 = *reinterpret_cast<const float4*>(p + 4);
            }
            short t8[8] = {f2bf(v0.x), f2bf(v0.y), f2bf(v0.z), f2bf(v0.w),
                           f2bf(v1.x), f2bf(v1.y), f2bf(v1.z), f2bf(v1.w)};
            *reinterpret_cast<bf16x8*>(&As[buf][kg * 1024 + (r ^ (kg << 2)) * 8]) =
                *reinterpret_cast<bf16x8*>(t8);
        }
    };
    // --- staging: W-tile -> Bs[buf]; wave w covers klocal = w*8..w*8+7, lane L = col
    auto stageB = [&](int kt, int buf) {
        int k0 = kt * 32 + w * 8;
        short t8[8];
        #pragma unroll
        for (int i = 0; i < 8; ++i) t8[i] = f2bf(W[(size_t)(k0 + i) * H1F + L]);
        int byteoff = L * 64 + ((w * 16) ^ ((L & 3) << 4));
        *reinterpret_cast<bf16x8*>((char*)Bs[buf] + byteoff) =
            *reinterpret_cast<bf16x8*>(t8);
    };
    auto compute = [&](int buf) {
        const int kg = L >> 4;            // 0..3  (k = kg*8 + i)
        const int lr = L & 15;
        int r0 = w * 32 + lr;
        int r1 = r0 + 16;
        bf16x8 a0 = *reinterpret_cast<bf16x8*>(&As[buf][kg * 1024 + (r0 ^ (kg << 2)) * 8]);
        bf16x8 a1 = *reinterpret_cast<bf16x8*>(&As[buf][kg * 1024 + (r1 ^ (kg << 2)) * 8]);
        #pragma unroll
        for (int ni = 0; ni < 4; ++ni) {
            int c = ni * 16 + lr;
            bf16x8 b = *reinterpret_cast<bf16x8*>(
                (char*)Bs[buf] + c * 64 + ((kg * 16) ^ ((c & 3) << 4)));
            acc[0][ni] = __builtin_amdgcn_mfma_f32_16x16x32_bf16(a0, b, acc[0][ni], 0, 0, 0);
            acc[1][ni] = __builtin_amdgcn_mfma_f32_16x16x32_bf16(a1, b, acc[1][ni], 0, 0, 0);
        }
    };

    stageA(0, 0);
    stageB(0, 0);
    __syncthreads();
    for (int kt = 0; kt < 16; ++kt) {
        int cur = kt & 1;
        if (kt < 15) {          // issue next-tile loads first (hide HBM latency)
            stageA(kt + 1, cur ^ 1);
            stageB(kt + 1, cur ^ 1);
        }
        compute(cur);
        __syncthreads();
    }

    // epilogue: D mapping col=lane&15, row=(lane>>4)*4+i  [m89-verified]
    #pragma unroll
    for (int mi = 0; mi < 2; ++mi) {
        #pragma unroll
        for (int i = 0; i < 4; ++i) {
            int row = brow + w * 32 + mi * 16 + (L >> 4) * 4 + i;
            if (row < N_NODES) {
                float dv = dinv[row];
                #pragma unroll
                for (int ni = 0; ni < 4; ++ni)
                    out[(size_t)row * H1F + ni * 16 + (L & 15)] = acc[mi][ni][i] * dv;
            }
        }
    }
}

// ---------------------------------------------------------------------------
// GEMM2: [N][64] @ [64][32], scaled by dinv.  8 rows/block.
// ---------------------------------------------------------------------------
__global__ __launch_bounds__(256) void gemm2_kernel(const float* __restrict__ h,
                                                    const float* __restrict__ W,
                                                    const float* __restrict__ dinv,
                                                    float* __restrict__ out) {
    __shared__ float ws[64][32];
    __shared__ float rs[8][64];
    int tid = threadIdx.x;
    int brow = blockIdx.x * 8;
    #pragma unroll
    for (int i = 0; i < 2; ++i) {
        int f = tid + i * 256;
        reinterpret_cast<float4*>(&ws[0][0])[f] = reinterpret_cast<const float4*>(W)[f];
    }
    if (tid < 128) {
        float4 v = reinterpret_cast<const float4*>(h)[(size_t)brow * 16 + tid];
        reinterpret_cast<float4*>(&rs[0][0])[tid] = v;
    }
    __syncthreads();
    int lr = tid >> 5;
    int c = tid & 31;
    float acc = 0.f;
    #pragma unroll
    for (int k = 0; k < 64; ++k) acc += rs[lr][k] * ws[k][c];
    int gr = brow + lr;
    out[(size_t)gr * H2F + c] = acc * dinv[gr];
}

// ---------------------------------------------------------------------------
// GEMM3: [N][32] @ [32][16], scaled by dinv.  16 rows/block.
// ---------------------------------------------------------------------------
__global__ __launch_bounds__(256) void gemm3_kernel(const float* __restrict__ h,
                                                    const float* __restrict__ W,
                                                    const float* __restrict__ dinv,
                                                    float* __restrict__ out) {
    __shared__ float ws[32][16];
    __shared__ float rs[16][32];
    int tid = threadIdx.x;
    int brow = blockIdx.x * 16;
    if (tid < 128) {
        reinterpret_cast<float4*>(&ws[0][0])[tid] = reinterpret_cast<const float4*>(W)[tid];
    } else {
        int t = tid - 128;
        float4 v = reinterpret_cast<const float4*>(h)[(size_t)brow * 8 + t];
        reinterpret_cast<float4*>(&rs[0][0])[t] = v;
    }
    __syncthreads();
    int lr = tid >> 4;
    int c = tid & 15;
    float acc = 0.f;
    #pragma unroll
    for (int k = 0; k < 32; ++k) acc += rs[lr][k] * ws[k][c];
    int gr = brow + lr;
    out[(size_t)gr * NCF + c] = acc * dinv[gr];
}

// ---------------------------------------------------------------------------
// Aggregate: out[n][f] = act( dinv[n] * (sum_{src in CSR[n]} h[src][f] + h[n][f]) + b[f] )
// 4-wide unrolled gather for MLP (memory-level parallelism).
// ---------------------------------------------------------------------------
template <int F, bool RELU, bool LSM>
__global__ __launch_bounds__(256) void aggregate_kernel(const float* __restrict__ h,
                                                        const int* __restrict__ row_ptr,
                                                        const int* __restrict__ col,
                                                        const float* __restrict__ dinv,
                                                        const float* __restrict__ bias,
                                                        float* __restrict__ out) {
    int tid = blockIdx.x * 256 + threadIdx.x;
    int n = tid / F;
    int f = tid % F;
    if (n >= N_NODES) return;
    int beg = row_ptr[n];
    int end = row_ptr[n + 1];
    float sum = h[(size_t)n * F + f];   // self-loop term (h already scaled by dinv)
    int j = beg;
    for (; j + 3 < end; j += 4) {
        int c0 = col[j], c1 = col[j + 1], c2 = col[j + 2], c3 = col[j + 3];
        float s0 = h[(size_t)c0 * F + f];
        float s1 = h[(size_t)c1 * F + f];
        float s2 = h[(size_t)c2 * F + f];
        float s3 = h[(size_t)c3 * F + f];
        sum += (s0 + s1) + (s2 + s3);
    }
    for (; j < end; ++j) sum += h[(size_t)col[j] * F + f];

    float val = sum * dinv[n] + bias[f];
    if (RELU) val = fmaxf(val, 0.f);
    if (LSM) {
        float m = val;
        #pragma unroll
        for (int o = 1; o < F; o <<= 1) m = fmaxf(m, __shfl_xor(m, o));
        float ex = expf(val - m);
        float s = ex;
        #pragma unroll
        for (int o = 1; o < F; o <<= 1) s += __shfl_xor(s, o);
        val = val - m - logf(s);
    }
    out[(size_t)n * F + f] = val;
}

// ---------------------------------------------------------------------------
extern "C" void kernel_launch(void* const* d_in, const int* in_sizes, int n_in,
                              void* d_out, int out_size, void* d_ws, size_t ws_size,
                              hipStream_t stream) {
    const float* x  = (const float*)d_in[0];
    const int*   ei = (const int*)d_in[1];
    const float* W1 = (const float*)d_in[2];
    const float* b1 = (const float*)d_in[3];
    const float* W2 = (const float*)d_in[4];
    const float* b2 = (const float*)d_in[5];
    const float* W3 = (const float*)d_in[6];
    const float* b3 = (const float*)d_in[7];
    float* out = (float*)d_out;

    const int* src = ei;              // edge_index[0]
    const int* dst = ei + N_EDGES;    // edge_index[1]

    char* ws = (char*)d_ws;
    size_t off = 0;
    auto alloc = [&](size_t bytes) -> void* {
        void* p = ws + off;
        off += (bytes + 255) & ~(size_t)255;
        return p;
    };
    int*   cnt     = (int*)alloc((size_t)N_NODES * 4);
    int*   row_ptr = (int*)alloc((size_t)(N_NODES + 1) * 4);
    int*   cursor  = (int*)alloc((size_t)N_NODES * 4);
    int*   bsums   = (int*)alloc(1024);
    float* dinv    = (float*)alloc((size_t)N_NODES * 4);
    int*   col     = (int*)alloc((size_t)N_EDGES * 4);
    float* bufA    = (float*)alloc((size_t)N_NODES * 64 * 4);
    float* bufB    = (float*)alloc((size_t)N_NODES * 64 * 4);

    const int nChunks = (N_NODES + 511) / 512;   // 196

    hipMemsetAsync(cnt, 0, (size_t)N_NODES * 4, stream);
    hist_kernel<<<(N_EDGES + 255) / 256, 256, 0, stream>>>(dst, cnt);
    scanA_kernel<<<nChunks, 512, 0, stream>>>(cnt, bsums);
    scanB_kernel<<<1, 256, 0, stream>>>(bsums, nChunks);
    scanC_kernel<<<nChunks, 512, 0, stream>>>(cnt, bsums, row_ptr, cursor);
    dinv_kernel<<<(N_NODES + 255) / 256, 256, 0, stream>>>(cnt, dinv);
    scatter_kernel<<<(N_EDGES + 255) / 256, 256, 0, stream>>>(src, dst, cursor, col);

    // Layer 1: x @ W1 (scaled, bf16 MFMA) -> bufA ; aggregate+bias+relu -> bufB
    gemm1_mfma<<<(N_NODES + 127) / 128, 256, 0, stream>>>(x, W1, dinv, bufA);
    aggregate_kernel<64, true, false><<<(N_NODES * 64) / 256, 256, 0, stream>>>(
        bufA, row_ptr, col, dinv, b1, bufB);

    // Layer 2: bufB @ W2 (scaled) -> bufA ; aggregate+bias+relu -> bufB
    gemm2_kernel<<<N_NODES / 8, 256, 0, stream>>>(bufB, W2, dinv, bufA);
    aggregate_kernel<32, true, false><<<(N_NODES * 32) / 256, 256, 0, stream>>>(
        bufA, row_ptr, col, dinv, b2, bufB);

    // Layer 3: bufB @ W3 (scaled) -> bufA ; aggregate+bias+log_softmax -> out
    gemm3_kernel<<<N_NODES / 16, 256, 0, stream>>>(bufB, W3, dinv, bufA);
    aggregate_kernel<16, false, true><<<(N_NODES * 16) / 256, 256, 0, stream>>>(
        bufA, row_ptr, col, dinv, b3, out);
}